// Round 1
// baseline (1461.737 us; speedup 1.0000x reference)
//
#include <hip/hip_runtime.h>
#include <utility>

// ---------------------------------------------------------------------------
// Compile-time real Clebsch-Gordan table (constexpr port of the reference)
// ---------------------------------------------------------------------------
namespace cg {

constexpr double FACT[13] = {1.,1.,2.,6.,24.,120.,720.,5040.,40320.,362880.,
                             3628800.,39916800.,479001600.};

constexpr double csqrt(double x){
  if (x <= 0.0) return 0.0;
  double g = x > 1.0 ? x : 1.0;
  for (int i = 0; i < 80; i++) g = 0.5*(g + x/g);
  return g;
}

constexpr double cg_complex(int j1,int m1,int j2,int m2,int j3,int m3){
  if (m1+m2 != m3) return 0.0;
  int dj = j1>j2 ? j1-j2 : j2-j1;
  if (j3 < dj || j3 > j1+j2) return 0.0;
  int am1 = m1<0?-m1:m1, am2 = m2<0?-m2:m2, am3 = m3<0?-m3:m3;
  if (am1>j1 || am2>j2 || am3>j3) return 0.0;
  double pref = csqrt((2.0*j3+1.0)*FACT[j3+j1-j2]*FACT[j3-j1+j2]*FACT[j1+j2-j3]
                      /FACT[j1+j2+j3+1]);
  pref *= csqrt(FACT[j3+m3]*FACT[j3-m3]*FACT[j1-m1]*FACT[j1+m1]
               *FACT[j2-m2]*FACT[j2+m2]);
  double s = 0.0;
  for (int k = 0; k <= j1+j2-j3; k++){
    int d1=j1+j2-j3-k, d2=j1-m1-k, d3=j2+m2-k, d4=j3-j2+m1+k, d5=j3-j1-m2+k;
    if (d1<0||d2<0||d3<0||d4<0||d5<0) continue;
    double den = FACT[k]*FACT[d1]*FACT[d2]*FACT[d3]*FACT[d4]*FACT[d5];
    s += ((k&1) ? -1.0 : 1.0)/den;
  }
  return pref*s;
}

struct CD { double re, im; };
struct UMat { CD m[9][9]; };

constexpr UMat makeU(int l){
  UMat U{};
  const double is2 = 1.0/csqrt(2.0);
  for (int mm = -l; mm <= l; mm++){
    int i = mm + l;
    if (mm > 0){
      U.m[i][ mm+l] = CD{((mm&1)?-1.0:1.0)*is2, 0.0};
      U.m[i][-mm+l] = CD{is2, 0.0};
    } else if (mm == 0){
      U.m[i][l] = CD{1.0, 0.0};
    } else {
      int nm = -mm;
      U.m[i][mm+l] = CD{0.0, is2};
      U.m[i][nm+l] = CD{0.0, -((nm&1)?-1.0:1.0)*is2};
    }
  }
  return U;
}

struct CGT { double c[5][5][9]; };

constexpr CGT realCG(int l1,int l2,int l3){
  double base[5][5][9] = {};
  for (int m1 = -l1; m1 <= l1; m1++)
    for (int m2 = -l2; m2 <= l2; m2++){
      int m3 = m1 + m2;
      if (m3 >= -l3 && m3 <= l3)
        base[m1+l1][m2+l2][m3+l3] = cg_complex(l1,m1,l2,m2,l3,m3);
    }
  UMat U1 = makeU(l1), U2 = makeU(l2), U3 = makeU(l3);
  CGT R{};
  const int n1 = 2*l1+1, n2 = 2*l2+1, n3 = 2*l3+1;
  const bool even = ((l1+l2+l3)&1) == 0;
  for (int a = 0; a < n1; a++)
    for (int b = 0; b < n2; b++)
      for (int c = 0; c < n3; c++){
        double sre = 0.0, sim = 0.0;
        for (int x = 0; x < n1; x++){
          CD u1 = U1.m[a][x];
          if (u1.re == 0.0 && u1.im == 0.0) continue;
          u1.im = -u1.im;                        // conj
          for (int y = 0; y < n2; y++){
            CD u2 = U2.m[b][y];
            if (u2.re == 0.0 && u2.im == 0.0) continue;
            u2.im = -u2.im;                      // conj
            CD t12{u1.re*u2.re - u1.im*u2.im, u1.re*u2.im + u1.im*u2.re};
            for (int z = 0; z < n3; z++){
              double bs = base[x][y][z];
              if (bs == 0.0) continue;
              CD u3 = U3.m[c][z];
              if (u3.re == 0.0 && u3.im == 0.0) continue;
              sre += (t12.re*u3.re - t12.im*u3.im)*bs;
              sim += (t12.re*u3.im + t12.im*u3.re)*bs;
            }
          }
        }
        R.c[a][b][c] = even ? sre : sim;
      }
  return R;
}

constexpr int MAXE = 805;
struct Table {
  int n, np;
  int oc[MAXE]; int ia[MAXE]; int ib[MAXE]; int ip[MAXE];
  float v[MAXE];
};

constexpr Table buildTable(){
  Table t{};
  int n = 0, p = 0;
  for (int l1 = 0; l1 <= 2; l1++)
    for (int l2 = 0; l2 <= 2; l2++){
      int lo = l1 > l2 ? l1-l2 : l2-l1;
      int hi = (l1+l2) < 4 ? (l1+l2) : 4;
      for (int l3 = lo; l3 <= hi; l3++){
        int par = (l1+l2+l3)&1;
        CGT C = realCG(l1,l2,l3);
        for (int a = 0; a < 2*l1+1; a++)
          for (int b = 0; b < 2*l2+1; b++)
            for (int c = 0; c < 2*l3+1; c++){
              double v = C.c[a][b][c];
              if (v > 1e-10 || v < -1e-10){
                t.oc[n] = par*25 + l3*l3 + c;
                t.ia[n] = l1*l1 + a;
                t.ib[n] = l2*l2 + b;
                t.ip[n] = p;
                t.v[n]  = (float)v;
                n++;
              }
            }
        p++;
      }
    }
  t.n = n; t.np = p;
  return t;
}

constexpr Table T = buildTable();
static_assert(T.np == 19, "path count mismatch vs reference PATHS");
static_assert(T.n >= 19 && T.n <= MAXE, "nnz sanity");

// Re-sorted by output channel so each of the 50 outputs can be computed to
// completion and stored immediately (kills the 50-register accumulator array).
struct Table2 {
  int off[51];
  int ia[MAXE]; int ib[MAXE]; int ip[MAXE];
  float v[MAXE];
};

constexpr Table2 buildTable2(){
  Table2 s{};
  int pos = 0;
  for (int oc = 0; oc < 50; oc++){
    s.off[oc] = pos;
    for (int e = 0; e < T.n; e++){
      if (T.oc[e] == oc){
        s.ia[pos] = T.ia[e]; s.ib[pos] = T.ib[e];
        s.ip[pos] = T.ip[e]; s.v[pos]  = T.v[e];
        pos++;
      }
    }
  }
  s.off[50] = pos;
  return s;
}

constexpr Table2 T2 = buildTable2();
static_assert(T2.off[50] == T.n, "resort lost entries");

} // namespace cg

// One output channel: fully unrolled compile-time-indexed accumulation.
template <int OC, int B, int... Ks>
__device__ __forceinline__ float tp_row(const float (&bx)[9], const float (&y2)[9],
                                        const float (&wv)[19],
                                        std::integer_sequence<int, Ks...>){
  float a = 0.0f;
  ((a += (cg::T2.v[B+Ks] * bx[cg::T2.ia[B+Ks]]) * (y2[cg::T2.ib[B+Ks]] * wv[cg::T2.ip[B+Ks]])), ...);
  return a;
}

template <int... OCs>
__device__ __forceinline__ void tp_store_all(const float (&bx)[9], const float (&y2)[9],
                                             const float (&wv)[19], float* __restrict__ op,
                                             std::integer_sequence<int, OCs...>){
  ((__builtin_nontemporal_store(
       tp_row<OCs, cg::T2.off[OCs]>(bx, y2, wv,
         std::make_integer_sequence<int, cg::T2.off[OCs+1] - cg::T2.off[OCs]>{}),
       op + OCs*32)), ...);
}

// ---------------------------------------------------------------------------
// One 32-lane group per edge (lane == feature), 8 groups per 256-thread block.
// Persistent-ish grid: each group loops over ~12 edges so that
//   - weights live in LDS, staged ONCE per block (no per-edge global reload)
//   - the random A-gather for edge e+stride is in flight under edge e's compute
//   - NI/D prefetched two edges ahead so gather addresses are always ready.
// No per-group barriers: LDS buffers are group-private and DS ops of a wave
// are processed in order.
// ---------------------------------------------------------------------------
__global__ __launch_bounds__(256, 4) void btmd_kernel(
    const float* __restrict__ A,  const int* __restrict__ NI,
    const float* __restrict__ D,
    const float* __restrict__ W1, const float* __restrict__ b1,
    const float* __restrict__ GM, const float* __restrict__ BT,
    const float* __restrict__ W2, const float* __restrict__ b2,
    const float* __restrict__ Wb, const float* __restrict__ bb,
    const float* __restrict__ TW, float* __restrict__ out, int nE)
{
  __shared__ alignas(16) float stg[8][288];     // [group][m*32+f]
  __shared__ alignas(16) float radl[8][32];     // [group][k]
  __shared__ alignas(16) float w1t[32*36];      // W1 transposed: [out g][in f], stride 36
  __shared__ alignas(16) float w2t[32*36];
  __shared__ alignas(16) float wbt[32*36];

  const int tid  = threadIdx.x;
  const int lane = tid & 31;
  const int grp  = tid >> 5;

  // ---- stage transposed weights to LDS (once per block) -------------------
  {
    const int idx = tid*4;                // covers 0..1023, 4 per thread
    const int f = idx >> 5, g = idx & 31; // source: row f, cols g..g+3
    const float4 a1 = *(const float4*)(W1 + idx);
    const float4 a2 = *(const float4*)(W2 + idx);
    const float4 a3 = *(const float4*)(Wb + idx);
    w1t[(g+0)*36+f]=a1.x; w1t[(g+1)*36+f]=a1.y; w1t[(g+2)*36+f]=a1.z; w1t[(g+3)*36+f]=a1.w;
    w2t[(g+0)*36+f]=a2.x; w2t[(g+1)*36+f]=a2.y; w2t[(g+2)*36+f]=a2.z; w2t[(g+3)*36+f]=a2.w;
    wbt[(g+0)*36+f]=a3.x; wbt[(g+1)*36+f]=a3.y; wbt[(g+2)*36+f]=a3.z; wbt[(g+3)*36+f]=a3.w;
  }

  // ---- loop-invariant per-lane parameters ---------------------------------
  float wv[19];
#pragma unroll
  for (int p = 0; p < 19; p++) wv[p] = TW[p*32 + lane];
  const float b1v = b1[lane], b2v = b2[lane], bbv = bb[lane];
  const float g0 = GM[lane], g1 = GM[32+lane], g2 = GM[64+lane], btv = BT[lane];

  __syncthreads();    // the only barrier: weights ready

  const int stride = gridDim.x * 8;
  int e = blockIdx.x * 8 + grp;
  if (e >= nE) return;

  // ---- pipeline state ------------------------------------------------------
  float pa[9], pb[9];                 // A-gather in flight for the CURRENT edge
  float cdx, cdy, cdz;                // displacement of current edge
  int   i1 = 0, j1 = 0;               // NI for edge e+stride
  float d1x = 0.f, d1y = 0.f, d1z = 0.f;
  int   i2 = 0, j2 = 0;               // NI for edge e+2*stride
  float d2x = 0.f, d2y = 0.f, d2z = 0.f;

  {
    const int2 nn = *(const int2*)(NI + 2*e);
    cdx = D[3*e]; cdy = D[3*e+1]; cdz = D[3*e+2];
    const float* Ai = A + (size_t)nn.x*288 + lane;
    const float* Aj = A + (size_t)nn.y*288 + lane;
#pragma unroll
    for (int m = 0; m < 9; m++){ pa[m] = Ai[m*32]; pb[m] = Aj[m*32]; }
    const int en1 = e + stride;
    if (en1 < nE){
      const int2 n1 = *(const int2*)(NI + 2*en1);
      i1 = n1.x; j1 = n1.y;
      d1x = D[3*en1]; d1y = D[3*en1+1]; d1z = D[3*en1+2];
    }
  }

  for (; e < nE; e += stride){
    const int en1 = e + stride;
    const int en2 = e + 2*stride;

    // ---- prefetch NI/D two edges ahead ------------------------------------
    if (en2 < nE){
      const int2 n2 = *(const int2*)(NI + 2*en2);
      i2 = n2.x; j2 = n2.y;
      d2x = D[3*en2]; d2y = D[3*en2+1]; d2z = D[3*en2+2];
    }

    // ---- consume current A-gather: stage A[i]+A[j] to LDS ------------------
#pragma unroll
    for (int m = 0; m < 9; m++) stg[grp][m*32 + lane] = pa[m] + pb[m];

    // ---- bond geometry + radial basis (lane == radial index k) ------------
    const float r    = sqrtf(cdx*cdx + cdy*cdy + cdz*cdz);
    const float rinv = 1.0f / fmaxf(r, 1e-12f);
    const float ux = cdx*rinv, uy = cdy*rinv, uz = cdz*rinv;
    {
      const float ck  = (5.0f/31.0f)*(float)lane;            // linspace(0,5,32)
      const float dr  = r - ck;
      const float cut = (r < 5.0f)
          ? 0.5f*(__cosf(0.6283185307179586f*r) + 1.0f) : 0.0f;  // pi/CUTOFF
      radl[grp][lane] = __expf(-20.48f*dr*dr) * cut;         // gamma=0.5*(32/5)^2
    }

    // ---- issue NEXT edge's A-gather (hidden under this edge's compute) -----
    if (en1 < nE){
      const float* Ai = A + (size_t)i1*288 + lane;
      const float* Aj = A + (size_t)j1*288 + lane;
#pragma unroll
      for (int m = 0; m < 9; m++){ pa[m] = Ai[m*32]; pb[m] = Aj[m*32]; }
    }

    // ---- dense1: y0[m] = sum_f yin[m][f]*W1[f][lane] (+b1 at m=0) ----------
    float y0[9];
    {
      float w1c[32];
      const float4* wp = (const float4*)&w1t[lane*36];
#pragma unroll
      for (int q = 0; q < 8; q++){
        float4 w = wp[q];
        w1c[4*q+0]=w.x; w1c[4*q+1]=w.y; w1c[4*q+2]=w.z; w1c[4*q+3]=w.w;
      }
#pragma unroll
      for (int m = 0; m < 9; m++){
        float acc = (m == 0) ? b1v : 0.0f;
        const float4* s4 = (const float4*)(&stg[grp][m*32]);
#pragma unroll
        for (int q = 0; q < 8; q++){
          float4 a = s4[q];
          acc += a.x*w1c[4*q+0] + a.y*w1c[4*q+1] + a.z*w1c[4*q+2] + a.w*w1c[4*q+3];
        }
        y0[m] = acc;
      }
    }

    // ---- layernorm stats (butterfly over the 32-lane group) ----------------
    const float s0 = y0[0];
    float sum0 = s0, sumsq0 = s0*s0;
    float ss1 = y0[1]*y0[1] + y0[2]*y0[2] + y0[3]*y0[3];
    float ss2 = y0[4]*y0[4] + y0[5]*y0[5] + y0[6]*y0[6] + y0[7]*y0[7] + y0[8]*y0[8];
#pragma unroll
    for (int off = 16; off >= 1; off >>= 1){
      sum0   += __shfl_xor(sum0,   off, 32);
      sumsq0 += __shfl_xor(sumsq0, off, 32);
      ss1    += __shfl_xor(ss1,    off, 32);
      ss2    += __shfl_xor(ss2,    off, 32);
    }
    const float mu  = sum0*(1.0f/32.0f);
    const float var = sumsq0*(1.0f/32.0f) - mu*mu;
    const float shat = (s0 - mu)*rsqrtf(var + 1e-6f)*g0 + btv;
    const float inv1 = rsqrtf(ss1*(1.0f/96.0f)  + 1e-6f)*g1;   // l=1: /(3*32)
    const float inv2 = rsqrtf(ss2*(1.0f/160.0f) + 1e-6f)*g2;   // l=2: /(5*32)

    // ---- mish gate ---------------------------------------------------------
    const float s    = shat;
    const float sp   = fmaxf(s, 0.0f) + log1pf(__expf(-fabsf(s)));  // softplus
    const float e2   = __expf(2.0f*sp);
    const float t    = 1.0f - 2.0f/(e2 + 1.0f);                      // tanh(sp)
    const float sig  = 1.0f/(1.0f + __expf(-s));
    const float dgat = t + s*(1.0f - t*t)*sig;
    const float act  = s*t;

    // ---- stage gated values; dense2 + residual -----------------------------
    stg[grp][lane] = act;
#pragma unroll
    for (int m = 1; m < 4; m++) stg[grp][m*32 + lane] = y0[m]*inv1*dgat;
#pragma unroll
    for (int m = 4; m < 9; m++) stg[grp][m*32 + lane] = y0[m]*inv2*dgat;

    float y2[9];
    {
      float w2c[32];
      const float4* wp = (const float4*)&w2t[lane*36];
#pragma unroll
      for (int q = 0; q < 8; q++){
        float4 w = wp[q];
        w2c[4*q+0]=w.x; w2c[4*q+1]=w.y; w2c[4*q+2]=w.z; w2c[4*q+3]=w.w;
      }
#pragma unroll
      for (int m = 0; m < 9; m++){
        float acc = (m == 0) ? b2v : 0.0f;
        const float4* s4 = (const float4*)(&stg[grp][m*32]);
#pragma unroll
        for (int q = 0; q < 8; q++){
          float4 a = s4[q];
          acc += a.x*w2c[4*q+0] + a.y*w2c[4*q+1] + a.z*w2c[4*q+2] + a.w*w2c[4*q+3];
        }
        y2[m] = acc + y0[m];
      }
    }

    // ---- radial projection: g = rad . Wb ----------------------------------
    float gf;
    {
      float wbc[32];
      const float4* wp = (const float4*)&wbt[lane*36];
#pragma unroll
      for (int q = 0; q < 8; q++){
        float4 w = wp[q];
        wbc[4*q+0]=w.x; wbc[4*q+1]=w.y; wbc[4*q+2]=w.z; wbc[4*q+3]=w.w;
      }
      float acc = 0.0f;
      const float4* r4 = (const float4*)(&radl[grp][0]);
#pragma unroll
      for (int q = 0; q < 8; q++){
        float4 a = r4[q];
        acc += a.x*wbc[4*q+0] + a.y*wbc[4*q+1] + a.z*wbc[4*q+2] + a.w*wbc[4*q+3];
      }
      gf = acc;
    }

    float bx[9];
    {
      const float S3 = 1.7320508075688772f;
      bx[0] = gf + bbv;
      bx[1] = uy*gf; bx[2] = uz*gf; bx[3] = ux*gf;
      bx[4] = S3*ux*uy*gf; bx[5] = S3*uy*uz*gf;
      bx[6] = 0.5f*(3.0f*uz*uz - 1.0f)*gf;
      bx[7] = S3*ux*uz*gf; bx[8] = 0.5f*S3*(ux*ux - uy*uy)*gf;
    }

    // ---- sparse CG tensor product, per-output-channel, store immediately ---
    float* op = out + (size_t)e*1600 + lane;
    tp_store_all(bx, y2, wv, op, std::make_integer_sequence<int, 50>{});

    // ---- rotate pipeline state ---------------------------------------------
    cdx = d1x; cdy = d1y; cdz = d1z;
    i1 = i2; j1 = j2; d1x = d2x; d1y = d2y; d1z = d2z;
  }
}

extern "C" void kernel_launch(void* const* d_in, const int* in_sizes, int n_in,
                              void* d_out, int out_size, void* d_ws, size_t ws_size,
                              hipStream_t stream)
{
  const float* A  = (const float*)d_in[0];   // (10000,1,9,32)
  const int*   NI = (const int*)  d_in[1];   // (100000,2)
  const float* D  = (const float*)d_in[2];   // (100000,3)
  const float* W1 = (const float*)d_in[3];
  const float* b1 = (const float*)d_in[4];
  const float* GM = (const float*)d_in[5];   // ln_gamma (3,32)
  const float* BT = (const float*)d_in[6];   // ln_beta (32)
  const float* W2 = (const float*)d_in[7];
  const float* b2 = (const float*)d_in[8];
  const float* Wb = (const float*)d_in[9];
  const float* bb = (const float*)d_in[10];
  const float* TW = (const float*)d_in[11];  // tp_w (19,32)
  float* out = (float*)d_out;

  const int nE = in_sizes[1] / 2;
  int grid = (nE + 7) / 8;
  if (grid > 1024) grid = 1024;              // persistent-ish: 4 blocks/CU resident
  btmd_kernel<<<dim3(grid), dim3(256), 0, stream>>>(A, NI, D, W1, b1, GM, BT,
                                                    W2, b2, Wb, bb, TW, out, nE);
}

// Round 2
// 822.369 us; speedup vs baseline: 1.7775x; 1.7775x over previous
//
#include <hip/hip_runtime.h>
#include <utility>

// ---------------------------------------------------------------------------
// Compile-time real Clebsch-Gordan table (constexpr port of the reference)
// ---------------------------------------------------------------------------
namespace cg {

constexpr double FACT[13] = {1.,1.,2.,6.,24.,120.,720.,5040.,40320.,362880.,
                             3628800.,39916800.,479001600.};

constexpr double csqrt(double x){
  if (x <= 0.0) return 0.0;
  double g = x > 1.0 ? x : 1.0;
  for (int i = 0; i < 80; i++) g = 0.5*(g + x/g);
  return g;
}

constexpr double cg_complex(int j1,int m1,int j2,int m2,int j3,int m3){
  if (m1+m2 != m3) return 0.0;
  int dj = j1>j2 ? j1-j2 : j2-j1;
  if (j3 < dj || j3 > j1+j2) return 0.0;
  int am1 = m1<0?-m1:m1, am2 = m2<0?-m2:m2, am3 = m3<0?-m3:m3;
  if (am1>j1 || am2>j2 || am3>j3) return 0.0;
  double pref = csqrt((2.0*j3+1.0)*FACT[j3+j1-j2]*FACT[j3-j1+j2]*FACT[j1+j2-j3]
                      /FACT[j1+j2+j3+1]);
  pref *= csqrt(FACT[j3+m3]*FACT[j3-m3]*FACT[j1-m1]*FACT[j1+m1]
               *FACT[j2-m2]*FACT[j2+m2]);
  double s = 0.0;
  for (int k = 0; k <= j1+j2-j3; k++){
    int d1=j1+j2-j3-k, d2=j1-m1-k, d3=j2+m2-k, d4=j3-j2+m1+k, d5=j3-j1-m2+k;
    if (d1<0||d2<0||d3<0||d4<0||d5<0) continue;
    double den = FACT[k]*FACT[d1]*FACT[d2]*FACT[d3]*FACT[d4]*FACT[d5];
    s += ((k&1) ? -1.0 : 1.0)/den;
  }
  return pref*s;
}

struct CD { double re, im; };
struct UMat { CD m[9][9]; };

constexpr UMat makeU(int l){
  UMat U{};
  const double is2 = 1.0/csqrt(2.0);
  for (int mm = -l; mm <= l; mm++){
    int i = mm + l;
    if (mm > 0){
      U.m[i][ mm+l] = CD{((mm&1)?-1.0:1.0)*is2, 0.0};
      U.m[i][-mm+l] = CD{is2, 0.0};
    } else if (mm == 0){
      U.m[i][l] = CD{1.0, 0.0};
    } else {
      int nm = -mm;
      U.m[i][mm+l] = CD{0.0, is2};
      U.m[i][nm+l] = CD{0.0, -((nm&1)?-1.0:1.0)*is2};
    }
  }
  return U;
}

struct CGT { double c[5][5][9]; };

constexpr CGT realCG(int l1,int l2,int l3){
  double base[5][5][9] = {};
  for (int m1 = -l1; m1 <= l1; m1++)
    for (int m2 = -l2; m2 <= l2; m2++){
      int m3 = m1 + m2;
      if (m3 >= -l3 && m3 <= l3)
        base[m1+l1][m2+l2][m3+l3] = cg_complex(l1,m1,l2,m2,l3,m3);
    }
  UMat U1 = makeU(l1), U2 = makeU(l2), U3 = makeU(l3);
  CGT R{};
  const int n1 = 2*l1+1, n2 = 2*l2+1, n3 = 2*l3+1;
  const bool even = ((l1+l2+l3)&1) == 0;
  for (int a = 0; a < n1; a++)
    for (int b = 0; b < n2; b++)
      for (int c = 0; c < n3; c++){
        double sre = 0.0, sim = 0.0;
        for (int x = 0; x < n1; x++){
          CD u1 = U1.m[a][x];
          if (u1.re == 0.0 && u1.im == 0.0) continue;
          u1.im = -u1.im;                        // conj
          for (int y = 0; y < n2; y++){
            CD u2 = U2.m[b][y];
            if (u2.re == 0.0 && u2.im == 0.0) continue;
            u2.im = -u2.im;                      // conj
            CD t12{u1.re*u2.re - u1.im*u2.im, u1.re*u2.im + u1.im*u2.re};
            for (int z = 0; z < n3; z++){
              double bs = base[x][y][z];
              if (bs == 0.0) continue;
              CD u3 = U3.m[c][z];
              if (u3.re == 0.0 && u3.im == 0.0) continue;
              sre += (t12.re*u3.re - t12.im*u3.im)*bs;
              sim += (t12.re*u3.im + t12.im*u3.re)*bs;
            }
          }
        }
        R.c[a][b][c] = even ? sre : sim;
      }
  return R;
}

constexpr int MAXE = 805;
struct Table {
  int n, np;
  int oc[MAXE]; int ia[MAXE]; int ib[MAXE]; int ip[MAXE];
  float v[MAXE];
};

constexpr Table buildTable(){
  Table t{};
  int n = 0, p = 0;
  for (int l1 = 0; l1 <= 2; l1++)
    for (int l2 = 0; l2 <= 2; l2++){
      int lo = l1 > l2 ? l1-l2 : l2-l1;
      int hi = (l1+l2) < 4 ? (l1+l2) : 4;
      for (int l3 = lo; l3 <= hi; l3++){
        int par = (l1+l2+l3)&1;
        CGT C = realCG(l1,l2,l3);
        for (int a = 0; a < 2*l1+1; a++)
          for (int b = 0; b < 2*l2+1; b++)
            for (int c = 0; c < 2*l3+1; c++){
              double v = C.c[a][b][c];
              if (v > 1e-10 || v < -1e-10){
                t.oc[n] = par*25 + l3*l3 + c;
                t.ia[n] = l1*l1 + a;
                t.ib[n] = l2*l2 + b;
                t.ip[n] = p;
                t.v[n]  = (float)v;
                n++;
              }
            }
        p++;
      }
    }
  t.n = n; t.np = p;
  return t;
}

constexpr Table T = buildTable();
static_assert(T.np == 19, "path count mismatch vs reference PATHS");
static_assert(T.n >= 19 && T.n <= MAXE, "nnz sanity");

// Re-sorted by output channel so each of the 50 outputs can be computed to
// completion and stored immediately (kills the 50-register accumulator array).
struct Table2 {
  int off[51];
  int ia[MAXE]; int ib[MAXE]; int ip[MAXE];
  float v[MAXE];
};

constexpr Table2 buildTable2(){
  Table2 s{};
  int pos = 0;
  for (int oc = 0; oc < 50; oc++){
    s.off[oc] = pos;
    for (int e = 0; e < T.n; e++){
      if (T.oc[e] == oc){
        s.ia[pos] = T.ia[e]; s.ib[pos] = T.ib[e];
        s.ip[pos] = T.ip[e]; s.v[pos]  = T.v[e];
        pos++;
      }
    }
  }
  s.off[50] = pos;
  return s;
}

constexpr Table2 T2 = buildTable2();
static_assert(T2.off[50] == T.n, "resort lost entries");

} // namespace cg

// One output channel: fully unrolled compile-time-indexed accumulation.
template <int OC, int B, int... Ks>
__device__ __forceinline__ float tp_row(const float (&bx)[9], const float (&y2)[9],
                                        const float (&wv)[19],
                                        std::integer_sequence<int, Ks...>){
  float a = 0.0f;
  ((a += (cg::T2.v[B+Ks] * bx[cg::T2.ia[B+Ks]]) * (y2[cg::T2.ib[B+Ks]] * wv[cg::T2.ip[B+Ks]])), ...);
  return a;
}

template <int... OCs>
__device__ __forceinline__ void tp_store_all(const float (&bx)[9], const float (&y2)[9],
                                             const float (&wv)[19], float* __restrict__ op,
                                             std::integer_sequence<int, OCs...>){
  ((__builtin_nontemporal_store(
       tp_row<OCs, cg::T2.off[OCs]>(bx, y2, wv,
         std::make_integer_sequence<int, cg::T2.off[OCs+1] - cg::T2.off[OCs]>{}),
       op + OCs*32)), ...);
}

// ---------------------------------------------------------------------------
// One 32-lane group per edge (lane == feature), 8 groups per 256-thread block.
// Persistent-ish grid: each group loops over ~12 edges so that
//   - weights live in LDS, staged ONCE per block (no per-edge global reload)
//   - the random A-gather for edge e+stride is in flight under edge e's compute
//   - NI/D prefetched two edges ahead so gather addresses are always ready.
// NOTE: NO min-waves clause in launch_bounds. Round-1 lesson: forcing 4
// waves/EU capped VGPRs at 64 and the ~150-reg live set spilled to scratch
// (FETCH_SIZE 1.56 GB, WRITE_SIZE 1.43 GB of pure spill traffic, 989 us).
// Let the allocator take ~200 regs; ILP pipeline + 2 waves/SIMD hide latency.
// ---------------------------------------------------------------------------
__global__ __launch_bounds__(256) void btmd_kernel(
    const float* __restrict__ A,  const int* __restrict__ NI,
    const float* __restrict__ D,
    const float* __restrict__ W1, const float* __restrict__ b1,
    const float* __restrict__ GM, const float* __restrict__ BT,
    const float* __restrict__ W2, const float* __restrict__ b2,
    const float* __restrict__ Wb, const float* __restrict__ bb,
    const float* __restrict__ TW, float* __restrict__ out, int nE)
{
  __shared__ alignas(16) float stg[8][288];     // [group][m*32+f]
  __shared__ alignas(16) float radl[8][32];     // [group][k]
  __shared__ alignas(16) float w1t[32*36];      // W1 transposed: [out g][in f], stride 36
  __shared__ alignas(16) float w2t[32*36];
  __shared__ alignas(16) float wbt[32*36];

  const int tid  = threadIdx.x;
  const int lane = tid & 31;
  const int grp  = tid >> 5;

  // ---- stage transposed weights to LDS (once per block) -------------------
  {
    const int idx = tid*4;                // covers 0..1023, 4 per thread
    const int f = idx >> 5, g = idx & 31; // source: row f, cols g..g+3
    const float4 a1 = *(const float4*)(W1 + idx);
    const float4 a2 = *(const float4*)(W2 + idx);
    const float4 a3 = *(const float4*)(Wb + idx);
    w1t[(g+0)*36+f]=a1.x; w1t[(g+1)*36+f]=a1.y; w1t[(g+2)*36+f]=a1.z; w1t[(g+3)*36+f]=a1.w;
    w2t[(g+0)*36+f]=a2.x; w2t[(g+1)*36+f]=a2.y; w2t[(g+2)*36+f]=a2.z; w2t[(g+3)*36+f]=a2.w;
    wbt[(g+0)*36+f]=a3.x; wbt[(g+1)*36+f]=a3.y; wbt[(g+2)*36+f]=a3.z; wbt[(g+3)*36+f]=a3.w;
  }

  // ---- loop-invariant per-lane parameters ---------------------------------
  float wv[19];
#pragma unroll
  for (int p = 0; p < 19; p++) wv[p] = TW[p*32 + lane];
  const float b1v = b1[lane], b2v = b2[lane], bbv = bb[lane];
  const float g0 = GM[lane], g1 = GM[32+lane], g2 = GM[64+lane], btv = BT[lane];

  __syncthreads();    // the only barrier: weights ready

  const int stride = gridDim.x * 8;
  int e = blockIdx.x * 8 + grp;
  if (e >= nE) return;

  // ---- pipeline state ------------------------------------------------------
  float pa[9], pb[9];                 // A-gather in flight for the CURRENT edge
  float cdx, cdy, cdz;                // displacement of current edge
  int   i1 = 0, j1 = 0;               // NI for edge e+stride
  float d1x = 0.f, d1y = 0.f, d1z = 0.f;
  int   i2 = 0, j2 = 0;               // NI for edge e+2*stride
  float d2x = 0.f, d2y = 0.f, d2z = 0.f;

  {
    const int2 nn = *(const int2*)(NI + 2*e);
    cdx = D[3*e]; cdy = D[3*e+1]; cdz = D[3*e+2];
    const float* Ai = A + (size_t)nn.x*288 + lane;
    const float* Aj = A + (size_t)nn.y*288 + lane;
#pragma unroll
    for (int m = 0; m < 9; m++){ pa[m] = Ai[m*32]; pb[m] = Aj[m*32]; }
    const int en1 = e + stride;
    if (en1 < nE){
      const int2 n1 = *(const int2*)(NI + 2*en1);
      i1 = n1.x; j1 = n1.y;
      d1x = D[3*en1]; d1y = D[3*en1+1]; d1z = D[3*en1+2];
    }
  }

  for (; e < nE; e += stride){
    const int en1 = e + stride;
    const int en2 = e + 2*stride;

    // ---- prefetch NI/D two edges ahead ------------------------------------
    if (en2 < nE){
      const int2 n2 = *(const int2*)(NI + 2*en2);
      i2 = n2.x; j2 = n2.y;
      d2x = D[3*en2]; d2y = D[3*en2+1]; d2z = D[3*en2+2];
    }

    // ---- consume current A-gather: stage A[i]+A[j] to LDS ------------------
#pragma unroll
    for (int m = 0; m < 9; m++) stg[grp][m*32 + lane] = pa[m] + pb[m];

    // ---- bond geometry + radial basis (lane == radial index k) ------------
    const float r    = sqrtf(cdx*cdx + cdy*cdy + cdz*cdz);
    const float rinv = 1.0f / fmaxf(r, 1e-12f);
    const float ux = cdx*rinv, uy = cdy*rinv, uz = cdz*rinv;
    {
      const float ck  = (5.0f/31.0f)*(float)lane;            // linspace(0,5,32)
      const float dr  = r - ck;
      const float cut = (r < 5.0f)
          ? 0.5f*(__cosf(0.6283185307179586f*r) + 1.0f) : 0.0f;  // pi/CUTOFF
      radl[grp][lane] = __expf(-20.48f*dr*dr) * cut;         // gamma=0.5*(32/5)^2
    }

    // ---- issue NEXT edge's A-gather (hidden under this edge's compute) -----
    if (en1 < nE){
      const float* Ai = A + (size_t)i1*288 + lane;
      const float* Aj = A + (size_t)j1*288 + lane;
#pragma unroll
      for (int m = 0; m < 9; m++){ pa[m] = Ai[m*32]; pb[m] = Aj[m*32]; }
    }

    // ---- dense1: y0[m] = sum_f yin[m][f]*W1[f][lane] (+b1 at m=0) ----------
    float y0[9];
    {
      float w1c[32];
      const float4* wp = (const float4*)&w1t[lane*36];
#pragma unroll
      for (int q = 0; q < 8; q++){
        float4 w = wp[q];
        w1c[4*q+0]=w.x; w1c[4*q+1]=w.y; w1c[4*q+2]=w.z; w1c[4*q+3]=w.w;
      }
#pragma unroll
      for (int m = 0; m < 9; m++){
        float acc = (m == 0) ? b1v : 0.0f;
        const float4* s4 = (const float4*)(&stg[grp][m*32]);
#pragma unroll
        for (int q = 0; q < 8; q++){
          float4 a = s4[q];
          acc += a.x*w1c[4*q+0] + a.y*w1c[4*q+1] + a.z*w1c[4*q+2] + a.w*w1c[4*q+3];
        }
        y0[m] = acc;
      }
    }

    // ---- layernorm stats (butterfly over the 32-lane group) ----------------
    const float s0 = y0[0];
    float sum0 = s0, sumsq0 = s0*s0;
    float ss1 = y0[1]*y0[1] + y0[2]*y0[2] + y0[3]*y0[3];
    float ss2 = y0[4]*y0[4] + y0[5]*y0[5] + y0[6]*y0[6] + y0[7]*y0[7] + y0[8]*y0[8];
#pragma unroll
    for (int off = 16; off >= 1; off >>= 1){
      sum0   += __shfl_xor(sum0,   off, 32);
      sumsq0 += __shfl_xor(sumsq0, off, 32);
      ss1    += __shfl_xor(ss1,    off, 32);
      ss2    += __shfl_xor(ss2,    off, 32);
    }
    const float mu  = sum0*(1.0f/32.0f);
    const float var = sumsq0*(1.0f/32.0f) - mu*mu;
    const float shat = (s0 - mu)*rsqrtf(var + 1e-6f)*g0 + btv;
    const float inv1 = rsqrtf(ss1*(1.0f/96.0f)  + 1e-6f)*g1;   // l=1: /(3*32)
    const float inv2 = rsqrtf(ss2*(1.0f/160.0f) + 1e-6f)*g2;   // l=2: /(5*32)

    // ---- mish gate ---------------------------------------------------------
    const float s    = shat;
    const float sp   = fmaxf(s, 0.0f) + log1pf(__expf(-fabsf(s)));  // softplus
    const float e2   = __expf(2.0f*sp);
    const float t    = 1.0f - 2.0f/(e2 + 1.0f);                      // tanh(sp)
    const float sig  = 1.0f/(1.0f + __expf(-s));
    const float dgat = t + s*(1.0f - t*t)*sig;
    const float act  = s*t;

    // ---- stage gated values; dense2 + residual -----------------------------
    stg[grp][lane] = act;
#pragma unroll
    for (int m = 1; m < 4; m++) stg[grp][m*32 + lane] = y0[m]*inv1*dgat;
#pragma unroll
    for (int m = 4; m < 9; m++) stg[grp][m*32 + lane] = y0[m]*inv2*dgat;

    float y2[9];
    {
      float w2c[32];
      const float4* wp = (const float4*)&w2t[lane*36];
#pragma unroll
      for (int q = 0; q < 8; q++){
        float4 w = wp[q];
        w2c[4*q+0]=w.x; w2c[4*q+1]=w.y; w2c[4*q+2]=w.z; w2c[4*q+3]=w.w;
      }
#pragma unroll
      for (int m = 0; m < 9; m++){
        float acc = (m == 0) ? b2v : 0.0f;
        const float4* s4 = (const float4*)(&stg[grp][m*32]);
#pragma unroll
        for (int q = 0; q < 8; q++){
          float4 a = s4[q];
          acc += a.x*w2c[4*q+0] + a.y*w2c[4*q+1] + a.z*w2c[4*q+2] + a.w*w2c[4*q+3];
        }
        y2[m] = acc + y0[m];
      }
    }

    // ---- radial projection: g = rad . Wb ----------------------------------
    float gf;
    {
      float wbc[32];
      const float4* wp = (const float4*)&wbt[lane*36];
#pragma unroll
      for (int q = 0; q < 8; q++){
        float4 w = wp[q];
        wbc[4*q+0]=w.x; wbc[4*q+1]=w.y; wbc[4*q+2]=w.z; wbc[4*q+3]=w.w;
      }
      float acc = 0.0f;
      const float4* r4 = (const float4*)(&radl[grp][0]);
#pragma unroll
      for (int q = 0; q < 8; q++){
        float4 a = r4[q];
        acc += a.x*wbc[4*q+0] + a.y*wbc[4*q+1] + a.z*wbc[4*q+2] + a.w*wbc[4*q+3];
      }
      gf = acc;
    }

    float bx[9];
    {
      const float S3 = 1.7320508075688772f;
      bx[0] = gf + bbv;
      bx[1] = uy*gf; bx[2] = uz*gf; bx[3] = ux*gf;
      bx[4] = S3*ux*uy*gf; bx[5] = S3*uy*uz*gf;
      bx[6] = 0.5f*(3.0f*uz*uz - 1.0f)*gf;
      bx[7] = S3*ux*uz*gf; bx[8] = 0.5f*S3*(ux*ux - uy*uy)*gf;
    }

    // ---- sparse CG tensor product, per-output-channel, store immediately ---
    float* op = out + (size_t)e*1600 + lane;
    tp_store_all(bx, y2, wv, op, std::make_integer_sequence<int, 50>{});

    // ---- rotate pipeline state ---------------------------------------------
    cdx = d1x; cdy = d1y; cdz = d1z;
    i1 = i2; j1 = j2; d1x = d2x; d1y = d2y; d1z = d2z;
  }
}

extern "C" void kernel_launch(void* const* d_in, const int* in_sizes, int n_in,
                              void* d_out, int out_size, void* d_ws, size_t ws_size,
                              hipStream_t stream)
{
  const float* A  = (const float*)d_in[0];   // (10000,1,9,32)
  const int*   NI = (const int*)  d_in[1];   // (100000,2)
  const float* D  = (const float*)d_in[2];   // (100000,3)
  const float* W1 = (const float*)d_in[3];
  const float* b1 = (const float*)d_in[4];
  const float* GM = (const float*)d_in[5];   // ln_gamma (3,32)
  const float* BT = (const float*)d_in[6];   // ln_beta (32)
  const float* W2 = (const float*)d_in[7];
  const float* b2 = (const float*)d_in[8];
  const float* Wb = (const float*)d_in[9];
  const float* bb = (const float*)d_in[10];
  const float* TW = (const float*)d_in[11];  // tp_w (19,32)
  float* out = (float*)d_out;

  const int nE = in_sizes[1] / 2;
  int grid = (nE + 7) / 8;
  if (grid > 1024) grid = 1024;              // persistent-ish
  btmd_kernel<<<dim3(grid), dim3(256), 0, stream>>>(A, NI, D, W1, b1, GM, BT,
                                                    W2, b2, Wb, bb, TW, out, nE);
}